// Round 11
// baseline (302.615 us; speedup 1.0000x reference)
//
#include <hip/hip_runtime.h>
#include <hip/hip_bf16.h>
#include <math.h>

#define B 4
#define H 256
#define W 256
#define HW 65536
#define BHW (B * HW)
#define LSTEPS 10
#define NCH 100
#define KS 51
#define KR 25

typedef __fp16 h2 __attribute__((ext_vector_type(2)));
typedef __fp16 half8 __attribute__((ext_vector_type(8)));
typedef float f32x4 __attribute__((ext_vector_type(4)));
typedef unsigned u32x4v __attribute__((ext_vector_type(4)));
typedef unsigned u32x2v __attribute__((ext_vector_type(2)));

static __device__ __forceinline__ h2 pack_f16(float a, float b) {
#if __has_builtin(__builtin_amdgcn_cvt_pkrtz)
    return __builtin_amdgcn_cvt_pkrtz(a, b);
#else
    h2 r; r.x = (__fp16)a; r.y = (__fp16)b; return r;
#endif
}
static __device__ __forceinline__ unsigned packu(float a, float b) {
    return __builtin_bit_cast(unsigned, pack_f16(a, b));
}

// ---------------- init: images[0]/residuals[0], gauss weights, f16 MFMA weight packs
// A1[i][112 rows][16 dw]: row c: dw t = (w1z[t], w1i[t]) t=0..8; dw9 = (bias, 0); dw10..15 = 0.
// A2[i][16 rows][64 dw]: row q: dw cp = (v2[2cp][q], v2[2cp+1][q]), 0 outside c<100,q<9.
__global__ void init_kernel(const float* __restrict__ src, const float* __restrict__ z0,
                            const float* __restrict__ conv1_w, const float* __restrict__ conv1_b,
                            const float* __restrict__ conv2_w,
                            float* __restrict__ images0, float* __restrict__ res0,
                            float* __restrict__ gw, unsigned* __restrict__ a1,
                            unsigned* __restrict__ a2) {
    int tid = blockIdx.x * 256 + threadIdx.x;   // 0 .. BHW-1
    images0[tid] = src[tid];
    res0[tid] = z0[tid & (HW - 1)];
    if (tid == 0) {
        float e[KS];
        float s = 0.f;
        for (int k = 0; k < KS; k++) {
            float x = (float)(k - KR) / 6.0f;
            e[k] = expf(-0.5f * x * x);
            s += e[k];
        }
        for (int k = 0; k < KS; k++) gw[k] = e[k] / s;
    }
    if (tid < LSTEPS * 112) {
        int i = tid / 112, c = tid % 112;
        unsigned* dst = a1 + (size_t)tid * 16;
        if (c < NCH) {
            const float* wz = conv1_w + ((size_t)i * NCH + c) * 18;
            float bias = conv1_b[(size_t)i * NCH + c];
#pragma unroll
            for (int t = 0; t < 9; t++) dst[t] = packu(wz[t], wz[9 + t]);
            dst[9] = packu(bias, 0.f);
#pragma unroll
            for (int t = 10; t < 16; t++) dst[t] = 0u;
        } else {
#pragma unroll
            for (int t = 0; t < 16; t++) dst[t] = 0u;
        }
    }
    if (tid >= 4096 && tid < 4096 + LSTEPS * 16) {
        int r = tid - 4096;
        int i = r / 16, q = r % 16;
        unsigned* dst = a2 + (size_t)r * 64;
        for (int cp = 0; cp < 64; cp++) {
            int c0 = 2 * cp, c1 = 2 * cp + 1;
            float f0 = (q < 9 && c0 < NCH) ? conv2_w[((size_t)i * NCH + c0) * 9 + q] : 0.f;
            float f1 = (q < 9 && c1 < NCH) ? conv2_w[((size_t)i * NCH + c1) * 9 + q] : 0.f;
            dst[cp] = packu(f0, f1);
        }
    }
}

// ---------------- MFMA resblock: sobel + im2col(LDS) + GEMM1(16x16x32 f16) + leaky
// + GEMM2 (S-map), one block per (b,row), 4 waves, each wave owns fixed 16-px slots.
__global__ __launch_bounds__(256, 4) void mfma_smap_kernel(
        const float* __restrict__ z, const float* __restrict__ img,
        const unsigned* __restrict__ a1, const unsigned* __restrict__ a2,
        __hip_bfloat16* __restrict__ S,
        float* __restrict__ grads_i, float* __restrict__ t) {
    __shared__ unsigned feat_l[256 * 16];   // [px][16 dw] = 32 f16 features, XOR-swz (px&3)
    __shared__ unsigned h_l[64 * 64];       // [px-slot][64 dw] = 128 f16 ch, XOR-swz (px&15)
    int bid = blockIdx.x;
    int b = bid >> 8, y = bid & 255;
    int x = threadIdx.x;
    int p = y * W + x;
    const float* zp = z + (b << 16);
    const float* ip = img + (b << 16);

    // patch loads: ri = raw clamped img (Sobel), fd = zero-padded (z,img) f16 pairs
    float ri[9];
    unsigned fd[16];
    float zc = 0.f;
#pragma unroll
    for (int dy = -1; dy <= 1; dy++) {
#pragma unroll
        for (int dx = -1; dx <= 1; dx++) {
            int yy = y + dy, xx = x + dx;
            bool ok = ((unsigned)yy < (unsigned)H) && ((unsigned)xx < (unsigned)W);
            int yc = min(max(yy, 0), H - 1);
            int xc = min(max(xx, 0), W - 1);
            int k = (dy + 1) * 3 + (dx + 1);
            float vz = zp[yc * W + xc], vi = ip[yc * W + xc];
            ri[k] = vi;
            float az = ok ? vz : 0.f, ai = ok ? vi : 0.f;
            if (k == 4) zc = az;
            fd[k] = packu(az, ai);
        }
    }
    float gx = ((ri[2] + 2.f * ri[5] + ri[8]) - (ri[0] + 2.f * ri[3] + ri[6])) * 0.125f;
    float gy = ((ri[6] + 2.f * ri[7] + ri[8]) - (ri[0] + 2.f * ri[1] + ri[2])) * 0.125f;
    grads_i[(b * 2 + 0) * HW + p] = gx;
    grads_i[(b * 2 + 1) * HW + p] = gy;
    t[(b * 2 + 0) * HW + p] = -zc * gx;
    t[(b * 2 + 1) * HW + p] = -zc * gy;

    fd[9] = packu(1.0f, 0.f);                // bias feature (k=18) = 1.0, k=19 = 0
#pragma unroll
    for (int k = 10; k < 16; k++) fd[k] = 0u;

    {   // feat write (swizzled)
        unsigned base = (unsigned)(x * 16);
        unsigned swzf = (unsigned)((x & 3) << 2);
#pragma unroll
        for (int g = 0; g < 4; g++) {
            u32x4v v = {fd[g * 4], fd[g * 4 + 1], fd[g * 4 + 2], fd[g * 4 + 3]};
            *(u32x4v*)(feat_l + base + ((unsigned)(g * 4) ^ swzf)) = v;
        }
    }
    if (x < 64) {   // zero h ch 112..127 (A2 weight 0 there; avoid NaN*0)
        unsigned swz0 = (unsigned)((x & 15) << 2);
        u32x4v zv = {0u, 0u, 0u, 0u};
        *(u32x4v*)(h_l + x * 64 + (56u ^ swz0)) = zv;
        *(u32x4v*)(h_l + x * 64 + (60u ^ swz0)) = zv;
    }

    int w = threadIdx.x >> 6;
    int lane = threadIdx.x & 63;
    int l15 = lane & 15, lg = lane >> 4;

    half8 A1f[7];
#pragma unroll
    for (int mt = 0; mt < 7; mt++)
        A1f[mt] = __builtin_bit_cast(half8,
            *(const u32x4v*)(a1 + (size_t)((mt * 16 + l15) * 16 + lg * 4)));
    half8 A2f[4];
#pragma unroll
    for (int ks = 0; ks < 4; ks++)
        A2f[ks] = __builtin_bit_cast(half8,
            *(const u32x4v*)(a2 + (size_t)(l15 * 64 + ks * 16 + lg * 4)));

    __syncthreads();

    unsigned hrow = (unsigned)((w * 16 + l15) * 64);
    unsigned swz = (unsigned)(l15 << 2);
    unsigned fswz = (unsigned)((l15 & 3) << 2);

#pragma unroll
    for (int qt = 0; qt < 4; qt++) {
        int pxq = qt * 64 + w * 16;
        half8 B1f = __builtin_bit_cast(half8,
            *(const u32x4v*)(feat_l + (unsigned)((pxq + l15) * 16) + ((unsigned)(lg * 4) ^ fswz)));
        f32x4 zero4 = {0.f, 0.f, 0.f, 0.f};
        f32x4 acc[7];
#pragma unroll
        for (int mt = 0; mt < 7; mt++)
            acc[mt] = __builtin_amdgcn_mfma_f32_16x16x32_f16(A1f[mt], B1f, zero4, 0, 0, 0);
        // leaky + pack f16 + store hidden (own slots; intra-wave ordering via lgkmcnt)
#pragma unroll
        for (int mt = 0; mt < 7; mt++) {
            float l0 = fmaxf(acc[mt][0], 0.01f * acc[mt][0]);
            float l1 = fmaxf(acc[mt][1], 0.01f * acc[mt][1]);
            float l2 = fmaxf(acc[mt][2], 0.01f * acc[mt][2]);
            float l3 = fmaxf(acc[mt][3], 0.01f * acc[mt][3]);
            u32x2v dv = {packu(l0, l1), packu(l2, l3)};
            unsigned c = (unsigned)(mt * 8 + lg * 2);
            *(u32x2v*)(h_l + hrow + (c ^ swz)) = dv;
        }
        f32x4 acc2 = {0.f, 0.f, 0.f, 0.f};
#pragma unroll
        for (int ks = 0; ks < 4; ks++) {
            half8 B2f = __builtin_bit_cast(half8,
                *(const u32x4v*)(h_l + hrow + ((unsigned)(ks * 16 + lg * 4) ^ swz)));
            acc2 = __builtin_amdgcn_mfma_f32_16x16x32_f16(A2f[ks], B2f, acc2, 0, 0, 0);
        }
        int xg = pxq + l15;
        size_t sbase = (size_t)(b << 16) + (size_t)y * W + xg;
#pragma unroll
        for (int r = 0; r < 4; r++) {
            int q = lg * 4 + r;
            if (q < 9) S[(size_t)q * BHW + sbase] = __float2bfloat16(acc2[r]);
        }
    }
}

// ---------------- FUSED vertical+horizontal blur + fields + S-gather + deform
// grid: B*H blocks, 256 threads. Each thread computes its column's 51-tap
// vertical sum on the fly (t is L2-resident), stages the row in LDS, then
// horizontal blur + conv2-finish + bilinear deform.
__global__ void vhblur_deform_kernel(const float* __restrict__ t, const float* __restrict__ gw,
                                     float* __restrict__ fields_i,
                                     const float* __restrict__ img, const float* __restrict__ z,
                                     const __hip_bfloat16* __restrict__ S,
                                     float* __restrict__ res_next, float* __restrict__ img_next) {
    int b = blockIdx.x >> 8;
    int row = blockIdx.x & 255;
    __shared__ float s0[W + 2 * KR], s1[W + 2 * KR];
    int x = threadIdx.x;

    // vertical blur at column x (rows zero-padded)
    const float* t0 = t + (b * 2 + 0) * HW;
    const float* t1 = t + (b * 2 + 1) * HW;
    float v0 = 0.f, v1 = 0.f;
#pragma unroll
    for (int k = 0; k < KS; k++) {
        int rr = row - KR + k;
        if ((unsigned)rr < (unsigned)H) {
            float wk = gw[k];
            v0 = fmaf(wk, t0[rr * W + x], v0);
            v1 = fmaf(wk, t1[rr * W + x], v1);
        }
    }
    s0[KR + x] = v0;
    s1[KR + x] = v1;
    if (x < KR) { s0[x] = 0.f; s1[x] = 0.f; }                       // left halo
    else if (x >= W - KR) { s0[x + 2 * KR] = 0.f; s1[x + 2 * KR] = 0.f; }  // right halo
    __syncthreads();

    // horizontal blur
    float a0 = 0.f, a1v = 0.f;
#pragma unroll
    for (int k = 0; k < KS; k++) {
        float wk = gw[k];
        a0 = fmaf(wk, s0[x + k], a0);
        a1v = fmaf(wk, s1[x + k], a1v);
    }
    int p = row * W + x;
    int tid = (b << 16) + p;
    float2* fdst = (float2*)(fields_i + (size_t)tid * 2);
    *fdst = make_float2(a0, a1v);

    // conv2 finish: out[y,x] = sum_q S_q[y-1+qy, x-1+qx], S == 0 outside image
    float f = 0.f;
#pragma unroll
    for (int q = 0; q < 9; q++) {
        int yy = row - 1 + q / 3;
        int xx = x - 1 + q % 3;
        if (((unsigned)yy < (unsigned)H) && ((unsigned)xx < (unsigned)W))
            f += __bfloat162float(S[(size_t)q * BHW + (b << 16) + yy * W + xx]);
    }
    float zn = z[tid] + f / 10.0f;
    res_next[tid] = zn;

    // bilinear deform
    float sx = (float)x - a0 / 10.0f;
    float sy = (float)row - a1v / 10.0f;
    float x0f = floorf(sx), y0f = floorf(sy);
    float wx = sx - x0f, wy = sy - y0f;
    int ix0 = min(max((int)x0f, 0), W - 1);
    int ix1 = min(max((int)x0f + 1, 0), W - 1);
    int iy0 = min(max((int)y0f, 0), H - 1);
    int iy1 = min(max((int)y0f + 1, 0), H - 1);
    const float* im = img + (b << 16);
    float Ia = im[iy0 * W + ix0], Ib = im[iy0 * W + ix1];
    float Ic = im[iy1 * W + ix0], Id = im[iy1 * W + ix1];
    float out = (1.f - wx) * (1.f - wy) * Ia + wx * (1.f - wy) * Ib
              + (1.f - wx) * wy * Ic + wx * wy * Id;
    img_next[tid] = out + zn * 0.001f;   // + z_next * MU^2 / L
}

extern "C" void kernel_launch(void* const* d_in, const int* in_sizes, int n_in,
                              void* d_out, int out_size, void* d_ws, size_t ws_size,
                              hipStream_t stream) {
    const float* source  = (const float*)d_in[0];
    const float* z0      = (const float*)d_in[1];
    const float* conv1_w = (const float*)d_in[2];
    const float* conv1_b = (const float*)d_in[3];
    const float* conv2_w = (const float*)d_in[4];

    float* out = (float*)d_out;
    float* images    = out;                              // [11][B][HW]
    float* fields    = images + (size_t)11 * B * HW;     // [10][B][HW][2]
    float* residuals = fields + (size_t)10 * B * HW * 2; // [11][B][HW]
    float* grads     = residuals + (size_t)11 * B * HW;  // [10][B][2][HW]

    float* ws = (float*)d_ws;
    float* t  = ws;                           // [B][2][HW] f32
    __hip_bfloat16* S = (__hip_bfloat16*)(t + (size_t)B * 2 * HW);   // [9][BHW] bf16
    float* gw = (float*)(S + (size_t)9 * BHW);                       // [64]
    unsigned* a1 = (unsigned*)(gw + 64);      // [10][112][16] dw
    unsigned* a2 = a1 + (size_t)LSTEPS * 112 * 16;  // [10][16][64] dw

    init_kernel<<<BHW / 256, 256, 0, stream>>>(source, z0, conv1_w, conv1_b, conv2_w,
                                               images, residuals, gw, a1, a2);

    for (int i = 0; i < LSTEPS; i++) {
        const float* img_i = images + (size_t)i * B * HW;
        const float* z_i   = residuals + (size_t)i * B * HW;
        float* fields_i    = fields + (size_t)i * B * HW * 2;

        mfma_smap_kernel<<<B * H, 256, 0, stream>>>(z_i, img_i,
                a1 + (size_t)i * 112 * 16, a2 + (size_t)i * 16 * 64, S,
                grads + (size_t)i * B * 2 * HW, t);
        vhblur_deform_kernel<<<B * H, 256, 0, stream>>>(t, gw, fields_i,
                img_i, z_i, S,
                residuals + (size_t)(i + 1) * B * HW, images + (size_t)(i + 1) * B * HW);
    }
}

// Round 12
// 276.762 us; speedup vs baseline: 1.0934x; 1.0934x over previous
//
#include <hip/hip_runtime.h>
#include <hip/hip_bf16.h>
#include <math.h>

#define B 4
#define H 256
#define W 256
#define HW 65536
#define BHW (B * HW)
#define LSTEPS 10
#define NCH 100
#define KS 51
#define KR 25

typedef __fp16 h2 __attribute__((ext_vector_type(2)));
typedef __fp16 half8 __attribute__((ext_vector_type(8)));
typedef float f32x4 __attribute__((ext_vector_type(4)));
typedef unsigned u32x4v __attribute__((ext_vector_type(4)));
typedef unsigned u32x2v __attribute__((ext_vector_type(2)));

static __device__ __forceinline__ h2 pack_f16(float a, float b) {
#if __has_builtin(__builtin_amdgcn_cvt_pkrtz)
    return __builtin_amdgcn_cvt_pkrtz(a, b);
#else
    h2 r; r.x = (__fp16)a; r.y = (__fp16)b; return r;
#endif
}
static __device__ __forceinline__ unsigned packu(float a, float b) {
    return __builtin_bit_cast(unsigned, pack_f16(a, b));
}

// ---------------- init: images[0]/residuals[0], gauss weights (f32 + packed f16 pairs),
// f16 MFMA weight packs.
// A1[i][112 rows][16 dw]: row c: dw t = (w1z[t], w1i[t]) t=0..8; dw9 = (bias, 0); dw10..15 = 0.
// A2[i][16 rows][64 dw]: row q: dw cp = (v2[2cp][q], v2[2cp+1][q]), 0 outside c<100,q<9.
__global__ void init_kernel(const float* __restrict__ src, const float* __restrict__ z0,
                            const float* __restrict__ conv1_w, const float* __restrict__ conv1_b,
                            const float* __restrict__ conv2_w,
                            float* __restrict__ images0, float* __restrict__ res0,
                            float* __restrict__ gw, unsigned* __restrict__ gwpk,
                            unsigned* __restrict__ a1, unsigned* __restrict__ a2) {
    int tid = blockIdx.x * 256 + threadIdx.x;   // 0 .. BHW-1
    images0[tid] = src[tid];
    res0[tid] = z0[tid & (HW - 1)];
    if (tid == 0) {
        float e[KS];
        float s = 0.f;
        for (int k = 0; k < KS; k++) {
            float x = (float)(k - KR) / 6.0f;
            e[k] = expf(-0.5f * x * x);
            s += e[k];
        }
        for (int k = 0; k < KS; k++) {
            float g = e[k] / s;
            gw[k] = g;
            gwpk[k] = packu(g, g);
        }
    }
    if (tid < LSTEPS * 112) {
        int i = tid / 112, c = tid % 112;
        unsigned* dst = a1 + (size_t)tid * 16;
        if (c < NCH) {
            const float* wz = conv1_w + ((size_t)i * NCH + c) * 18;
            float bias = conv1_b[(size_t)i * NCH + c];
#pragma unroll
            for (int t = 0; t < 9; t++) dst[t] = packu(wz[t], wz[9 + t]);
            dst[9] = packu(bias, 0.f);
#pragma unroll
            for (int t = 10; t < 16; t++) dst[t] = 0u;
        } else {
#pragma unroll
            for (int t = 0; t < 16; t++) dst[t] = 0u;
        }
    }
    if (tid >= 4096 && tid < 4096 + LSTEPS * 16) {
        int r = tid - 4096;
        int i = r / 16, q = r % 16;
        unsigned* dst = a2 + (size_t)r * 64;
        for (int cp = 0; cp < 64; cp++) {
            int c0 = 2 * cp, c1 = 2 * cp + 1;
            float f0 = (q < 9 && c0 < NCH) ? conv2_w[((size_t)i * NCH + c0) * 9 + q] : 0.f;
            float f1 = (q < 9 && c1 < NCH) ? conv2_w[((size_t)i * NCH + c1) * 9 + q] : 0.f;
            dst[cp] = packu(f0, f1);
        }
    }
}

// ---------------- MFMA resblock: sobel + im2col(LDS) + GEMM1(16x16x32 f16) + leaky
// + GEMM2 (S-map), one block per (b,row), 4 waves, each wave owns fixed 16-px slots.
// t written as ONE packed dword per pixel: (tx, ty) f16.
__global__ __launch_bounds__(256, 4) void mfma_smap_kernel(
        const float* __restrict__ z, const float* __restrict__ img,
        const unsigned* __restrict__ a1, const unsigned* __restrict__ a2,
        __hip_bfloat16* __restrict__ S,
        float* __restrict__ grads_i, unsigned* __restrict__ t01) {
    __shared__ unsigned feat_l[256 * 16];   // [px][16 dw] = 32 f16 features, XOR-swz (px&3)
    __shared__ unsigned h_l[64 * 64];       // [px-slot][64 dw] = 128 f16 ch, XOR-swz (px&15)
    int bid = blockIdx.x;
    int b = bid >> 8, y = bid & 255;
    int x = threadIdx.x;
    int p = y * W + x;
    const float* zp = z + (b << 16);
    const float* ip = img + (b << 16);

    // patch loads: ri = raw clamped img (Sobel), fd = zero-padded (z,img) f16 pairs
    float ri[9];
    unsigned fd[16];
    float zc = 0.f;
#pragma unroll
    for (int dy = -1; dy <= 1; dy++) {
#pragma unroll
        for (int dx = -1; dx <= 1; dx++) {
            int yy = y + dy, xx = x + dx;
            bool ok = ((unsigned)yy < (unsigned)H) && ((unsigned)xx < (unsigned)W);
            int yc = min(max(yy, 0), H - 1);
            int xc = min(max(xx, 0), W - 1);
            int k = (dy + 1) * 3 + (dx + 1);
            float vz = zp[yc * W + xc], vi = ip[yc * W + xc];
            ri[k] = vi;
            float az = ok ? vz : 0.f, ai = ok ? vi : 0.f;
            if (k == 4) zc = az;
            fd[k] = packu(az, ai);
        }
    }
    float gx = ((ri[2] + 2.f * ri[5] + ri[8]) - (ri[0] + 2.f * ri[3] + ri[6])) * 0.125f;
    float gy = ((ri[6] + 2.f * ri[7] + ri[8]) - (ri[0] + 2.f * ri[1] + ri[2])) * 0.125f;
    grads_i[(b * 2 + 0) * HW + p] = gx;
    grads_i[(b * 2 + 1) * HW + p] = gy;
    t01[(b << 16) + p] = packu(-zc * gx, -zc * gy);

    fd[9] = packu(1.0f, 0.f);                // bias feature (k=18) = 1.0, k=19 = 0
#pragma unroll
    for (int k = 10; k < 16; k++) fd[k] = 0u;

    {   // feat write (swizzled)
        unsigned base = (unsigned)(x * 16);
        unsigned swzf = (unsigned)((x & 3) << 2);
#pragma unroll
        for (int g = 0; g < 4; g++) {
            u32x4v v = {fd[g * 4], fd[g * 4 + 1], fd[g * 4 + 2], fd[g * 4 + 3]};
            *(u32x4v*)(feat_l + base + ((unsigned)(g * 4) ^ swzf)) = v;
        }
    }
    if (x < 64) {   // zero h ch 112..127 (A2 weight 0 there; avoid NaN*0)
        unsigned swz0 = (unsigned)((x & 15) << 2);
        u32x4v zv = {0u, 0u, 0u, 0u};
        *(u32x4v*)(h_l + x * 64 + (56u ^ swz0)) = zv;
        *(u32x4v*)(h_l + x * 64 + (60u ^ swz0)) = zv;
    }

    int w = threadIdx.x >> 6;
    int lane = threadIdx.x & 63;
    int l15 = lane & 15, lg = lane >> 4;

    half8 A1f[7];
#pragma unroll
    for (int mt = 0; mt < 7; mt++)
        A1f[mt] = __builtin_bit_cast(half8,
            *(const u32x4v*)(a1 + (size_t)((mt * 16 + l15) * 16 + lg * 4)));
    half8 A2f[4];
#pragma unroll
    for (int ks = 0; ks < 4; ks++)
        A2f[ks] = __builtin_bit_cast(half8,
            *(const u32x4v*)(a2 + (size_t)(l15 * 64 + ks * 16 + lg * 4)));

    __syncthreads();

    unsigned hrow = (unsigned)((w * 16 + l15) * 64);
    unsigned swz = (unsigned)(l15 << 2);
    unsigned fswz = (unsigned)((l15 & 3) << 2);

#pragma unroll
    for (int qt = 0; qt < 4; qt++) {
        int pxq = qt * 64 + w * 16;
        half8 B1f = __builtin_bit_cast(half8,
            *(const u32x4v*)(feat_l + (unsigned)((pxq + l15) * 16) + ((unsigned)(lg * 4) ^ fswz)));
        f32x4 zero4 = {0.f, 0.f, 0.f, 0.f};
        f32x4 acc[7];
#pragma unroll
        for (int mt = 0; mt < 7; mt++)
            acc[mt] = __builtin_amdgcn_mfma_f32_16x16x32_f16(A1f[mt], B1f, zero4, 0, 0, 0);
        // leaky + pack f16 + store hidden (own slots; intra-wave ordering via lgkmcnt)
#pragma unroll
        for (int mt = 0; mt < 7; mt++) {
            float l0 = fmaxf(acc[mt][0], 0.01f * acc[mt][0]);
            float l1 = fmaxf(acc[mt][1], 0.01f * acc[mt][1]);
            float l2 = fmaxf(acc[mt][2], 0.01f * acc[mt][2]);
            float l3 = fmaxf(acc[mt][3], 0.01f * acc[mt][3]);
            u32x2v dv = {packu(l0, l1), packu(l2, l3)};
            unsigned c = (unsigned)(mt * 8 + lg * 2);
            *(u32x2v*)(h_l + hrow + (c ^ swz)) = dv;
        }
        f32x4 acc2 = {0.f, 0.f, 0.f, 0.f};
#pragma unroll
        for (int ks = 0; ks < 4; ks++) {
            half8 B2f = __builtin_bit_cast(half8,
                *(const u32x4v*)(h_l + hrow + ((unsigned)(ks * 16 + lg * 4) ^ swz)));
            acc2 = __builtin_amdgcn_mfma_f32_16x16x32_f16(A2f[ks], B2f, acc2, 0, 0, 0);
        }
        int xg = pxq + l15;
        size_t sbase = (size_t)(b << 16) + (size_t)y * W + xg;
#pragma unroll
        for (int r = 0; r < 4; r++) {
            int q = lg * 4 + r;
            if (q < 9) S[(size_t)q * BHW + sbase] = __float2bfloat16(acc2[r]);
        }
    }
}

// ---------------- FUSED packed-f16 vertical+horizontal blur + fields + S-gather + deform
// grid: B*H blocks, 256 threads. t packed as (tx,ty) f16 per px; both blur passes
// in v_pk_fma_f16 with 3 interleaved accumulators (static-indexed).
__global__ void vhblur_deform_kernel(const unsigned* __restrict__ t01g,
                                     const unsigned* __restrict__ gwpk,
                                     float* __restrict__ fields_i,
                                     const float* __restrict__ img, const float* __restrict__ z,
                                     const __hip_bfloat16* __restrict__ S,
                                     float* __restrict__ res_next, float* __restrict__ img_next) {
    int b = blockIdx.x >> 8;
    int row = blockIdx.x & 255;
    __shared__ unsigned s01[W + 2 * KR];
    int x = threadIdx.x;

    // vertical blur at column x (rows zero-padded), packed f16 both channels
    const unsigned* t01 = t01g + (b << 16);
    h2 vacc[3];
#pragma unroll
    for (int j = 0; j < 3; j++) { h2 zz = {(__fp16)0.f, (__fp16)0.f}; vacc[j] = zz; }
#pragma unroll
    for (int k = 0; k < KS; k++) {
        int rr = row - KR + k;
        if ((unsigned)rr < (unsigned)H) {
            h2 tv = __builtin_bit_cast(h2, t01[rr * W + x]);
            h2 wv = __builtin_bit_cast(h2, gwpk[k]);
            vacc[k % 3] = wv * tv + vacc[k % 3];
        }
    }
    h2 v01 = vacc[0] + vacc[1] + vacc[2];
    s01[KR + x] = __builtin_bit_cast(unsigned, v01);
    if (x < KR) s01[x] = 0u;                             // left halo
    else if (x >= W - KR) s01[x + 2 * KR] = 0u;          // right halo
    __syncthreads();

    // horizontal blur, packed f16
    h2 hacc[3];
#pragma unroll
    for (int j = 0; j < 3; j++) { h2 zz = {(__fp16)0.f, (__fp16)0.f}; hacc[j] = zz; }
#pragma unroll
    for (int k = 0; k < KS; k++) {
        h2 sv = __builtin_bit_cast(h2, s01[x + k]);
        h2 wv = __builtin_bit_cast(h2, gwpk[k]);
        hacc[k % 3] = wv * sv + hacc[k % 3];
    }
    h2 a01 = hacc[0] + hacc[1] + hacc[2];
    float a0 = (float)a01.x, a1v = (float)a01.y;

    int p = row * W + x;
    int tid = (b << 16) + p;
    float2* fdst = (float2*)(fields_i + (size_t)tid * 2);
    *fdst = make_float2(a0, a1v);

    // conv2 finish: out[y,x] = sum_q S_q[y-1+qy, x-1+qx], S == 0 outside image
    float f = 0.f;
#pragma unroll
    for (int q = 0; q < 9; q++) {
        int yy = row - 1 + q / 3;
        int xx = x - 1 + q % 3;
        if (((unsigned)yy < (unsigned)H) && ((unsigned)xx < (unsigned)W))
            f += __bfloat162float(S[(size_t)q * BHW + (b << 16) + yy * W + xx]);
    }
    float zn = z[tid] + f / 10.0f;
    res_next[tid] = zn;

    // bilinear deform
    float sx = (float)x - a0 / 10.0f;
    float sy = (float)row - a1v / 10.0f;
    float x0f = floorf(sx), y0f = floorf(sy);
    float wx = sx - x0f, wy = sy - y0f;
    int ix0 = min(max((int)x0f, 0), W - 1);
    int ix1 = min(max((int)x0f + 1, 0), W - 1);
    int iy0 = min(max((int)y0f, 0), H - 1);
    int iy1 = min(max((int)y0f + 1, 0), H - 1);
    const float* im = img + (b << 16);
    float Ia = im[iy0 * W + ix0], Ib = im[iy0 * W + ix1];
    float Ic = im[iy1 * W + ix0], Id = im[iy1 * W + ix1];
    float out = (1.f - wx) * (1.f - wy) * Ia + wx * (1.f - wy) * Ib
              + (1.f - wx) * wy * Ic + wx * wy * Id;
    img_next[tid] = out + zn * 0.001f;   // + z_next * MU^2 / L
}

extern "C" void kernel_launch(void* const* d_in, const int* in_sizes, int n_in,
                              void* d_out, int out_size, void* d_ws, size_t ws_size,
                              hipStream_t stream) {
    const float* source  = (const float*)d_in[0];
    const float* z0      = (const float*)d_in[1];
    const float* conv1_w = (const float*)d_in[2];
    const float* conv1_b = (const float*)d_in[3];
    const float* conv2_w = (const float*)d_in[4];

    float* out = (float*)d_out;
    float* images    = out;                              // [11][B][HW]
    float* fields    = images + (size_t)11 * B * HW;     // [10][B][HW][2]
    float* residuals = fields + (size_t)10 * B * HW * 2; // [11][B][HW]
    float* grads     = residuals + (size_t)11 * B * HW;  // [10][B][2][HW]

    unsigned* t01 = (unsigned*)d_ws;                     // [B][HW] packed (tx,ty) f16
    __hip_bfloat16* S = (__hip_bfloat16*)(t01 + (size_t)BHW);        // [9][BHW] bf16
    float* gw = (float*)(S + (size_t)9 * BHW);                       // [64]
    unsigned* gwpk = (unsigned*)(gw + 64);                           // [64]
    unsigned* a1 = gwpk + 64;                 // [10][112][16] dw
    unsigned* a2 = a1 + (size_t)LSTEPS * 112 * 16;  // [10][16][64] dw

    init_kernel<<<BHW / 256, 256, 0, stream>>>(source, z0, conv1_w, conv1_b, conv2_w,
                                               images, residuals, gw, gwpk, a1, a2);

    for (int i = 0; i < LSTEPS; i++) {
        const float* img_i = images + (size_t)i * B * HW;
        const float* z_i   = residuals + (size_t)i * B * HW;
        float* fields_i    = fields + (size_t)i * B * HW * 2;

        mfma_smap_kernel<<<B * H, 256, 0, stream>>>(z_i, img_i,
                a1 + (size_t)i * 112 * 16, a2 + (size_t)i * 16 * 64, S,
                grads + (size_t)i * B * 2 * HW, t01);
        vhblur_deform_kernel<<<B * H, 256, 0, stream>>>(t01, gwpk, fields_i,
                img_i, z_i, S,
                residuals + (size_t)(i + 1) * B * HW, images + (size_t)(i + 1) * B * HW);
    }
}